// Round 11
// baseline (575.524 us; speedup 1.0000x reference)
//
#include <hip/hip_runtime.h>

#define FOUR_H 128
#define FUT 6
#define BSZ 256
#define TT 2048
#define FF 64
#define CH 16
#define NCH (TT / CH)              // 128 chunks of 16 timesteps

typedef float f32x2 __attribute__((ext_vector_type(2)));
typedef float f32x4 __attribute__((ext_vector_type(4)));
typedef unsigned int u32;
typedef u32 u32x4 __attribute__((ext_vector_type(4)));
typedef short bf16x8 __attribute__((ext_vector_type(8)));

__device__ __forceinline__ float fast_rcp(float x)  { return __builtin_amdgcn_rcpf(x); }
__device__ __forceinline__ float fast_exp2(float x) { return __builtin_amdgcn_exp2f(x); }
__device__ __forceinline__ float sigmoid_f(float x) {
    float t = fast_exp2(x * -1.44269504088896340736f);
    return fast_rcp(1.0f + t);
}
__device__ __forceinline__ u32 f2u(float x) { return __builtin_bit_cast(u32, x); }
__device__ __forceinline__ float u2f(u32 x) { return __builtin_bit_cast(float, x); }

__device__ __forceinline__ void gload_lds16(const void* g, void* l) {
    __builtin_amdgcn_global_load_lds(
        (const __attribute__((address_space(1))) void*)g,
        (__attribute__((address_space(3))) void*)l, 16, 0, 0);
}

__device__ __forceinline__ f32x4 mfma16(bf16x8 a, bf16x8 b, f32x4 c) {
    return __builtin_amdgcn_mfma_f32_16x16x32_bf16(a, b, c, 0, 0, 0);
}

// ===========================================================================
// 128 blocks x 8 waves; block B owns batches 2B and 2B+1.
// Wave->SIMD is round-robin (wave i -> SIMD i%4):
//   waves 0,4 : consumers (chains ci=0,1)  -> BOTH on SIMD0. A lone wave
//               issues at ~4cy/inst; two co-resident consumer waves fill each
//               other's issue slots and LDS/trans stall windows.
//   waves 1,5 : producers (X gload + split-bf16 MFMA x-proj) -> SIMD1.
//   waves 2,3,6,7 : idle (barrier-matching loop only).
// Per-chain private xstage/zbuf/sh slabs; Wx fragments live in producer regs.
// ===========================================================================
__global__ __launch_bounds__(512) void lstm_fused(
    const float* __restrict__ X, const float* __restrict__ Wx,
    const float* __restrict__ bias, const float* __restrict__ Wh,
    const float* __restrict__ Wd, const float* __restrict__ bd,
    float* __restrict__ out)
{
    __shared__ float xstage[2][2 * CH * FF];     // 16 KB  X dbuf per chain
    __shared__ float zbuf[2][2 * CH * FOUR_H];   // 32 KB  Z dbuf per chain
    __shared__ float sh[2][32];                  // h broadcast slabs

    int wv   = threadIdx.x >> 6;
    int role = wv & 3;          // 0=consumer, 1=producer, 2/3=idle
    int ci   = wv >> 2;         // chain index within block
    int b    = blockIdx.x * 2 + ci;
    int l    = threadIdx.x & 63;
    int kl = l & 31;
    int lr = l >> 4;
    int lc = l & 15;
    bool lowHalf = (l < 32);

    const u32 PSEL = 0x07060302u;
    const char* Xb = (const char*)(X + (size_t)b * TT * FF);

    float* xstageC = xstage[ci];
    float* zbufC   = zbuf[ci];
    float* shC     = sh[ci];
    const float4* shq = (const float4*)shC;

    // ---------------- consumer state ----------------
    f32x2 wh0p[16], wh1p[16];
    float c = 0.0f, h = 0.0f;
    const float L2E = 1.44269504088896340736f;
    float s1 = lowHalf ? (-2.0f * L2E) : (-L2E);
    float m1 = lowHalf ? 2.0f : 1.0f;
    float a1 = lowHalf ? -1.0f : 0.0f;

    // ---------------- producer state ----------------
    float bj[8];
    int soff[4];
    u32x4 wregH[16], wregL[16];   // Wx bf16 hi/lo fragments in registers

    if (role == 0) {
#pragma unroll
        for (int m = 0; m < 16; ++m) {
            wh0p[m][0] = Wh[(2 * m) * FOUR_H + l];
            wh0p[m][1] = Wh[(2 * m + 1) * FOUR_H + l];
            wh1p[m][0] = Wh[(2 * m) * FOUR_H + 64 + l];
            wh1p[m][1] = Wh[(2 * m + 1) * FOUR_H + 64 + l];
        }
    } else if (role == 1) {
#pragma unroll
        for (int n = 0; n < 8; ++n) bj[n] = bias[n * 16 + lc];
#pragma unroll
        for (int i = 0; i < 4; ++i) {
            int t = i * 4 + lr;
            soff[i] = t * 256 + ((lc ^ t) << 4);
        }
        // split Wx into bf16 hi/lo B-fragments, kept in registers.
        // frag (n,ks): lane l holds B[k][j], j=n*16+lc, k=ks*32+lr*8+e.
#pragma unroll 2
        for (int n = 0; n < 8; ++n)
            for (int ks = 0; ks < 2; ++ks) {
                u32 hi[4], lo[4];
#pragma unroll
                for (int e = 0; e < 4; ++e) {
                    int k0 = ks * 32 + lr * 8 + 2 * e;
                    float w0 = Wx[k0 * FOUR_H + n * 16 + lc];
                    float w1 = Wx[(k0 + 1) * FOUR_H + n * 16 + lc];
                    u32 x0 = f2u(w0), x1 = f2u(w1);
                    hi[e] = __builtin_amdgcn_perm(x1, x0, PSEL);
                    float l0 = w0 - u2f(x0 & 0xFFFF0000u);
                    float l1 = w1 - u2f(x1 & 0xFFFF0000u);
                    lo[e] = __builtin_amdgcn_perm(f2u(l1), f2u(l0), PSEL);
                }
                wregH[n * 2 + ks] = (u32x4){hi[0], hi[1], hi[2], hi[3]};
                wregL[n * 2 + ks] = (u32x4){lo[0], lo[1], lo[2], lo[3]};
            }
    }

#define GLOAD(mm)                                                            \
    {                                                                        \
        const char* src = Xb + (size_t)(mm) * 4096;                          \
        char* dst = (char*)xstageC + ((mm) & 1) * 4096;                      \
        _Pragma("unroll")                                                    \
        for (int i = 0; i < 4; ++i)                                          \
            gload_lds16(src + soff[i], dst + i * 1024);                      \
    }

#define ZPREP(mm)                                                            \
    {                                                                        \
        f32x4 zacc[8];                                                       \
        _Pragma("unroll")                                                    \
        for (int n = 0; n < 8; ++n)                                          \
            zacc[n] = (f32x4){bj[n], bj[n], bj[n], bj[n]};                   \
        const char* xs = (const char*)xstageC + ((mm) & 1) * 4096;           \
        _Pragma("unroll")                                                    \
        for (int ks = 0; ks < 2; ++ks) {                                     \
            int q0 = ks * 8 + lr * 2;                                        \
            int aoff = lc * 256 + ((q0 ^ lc) << 4);                          \
            u32x4 xa = *(const u32x4*)(xs + aoff);                           \
            u32x4 xv = *(const u32x4*)(xs + (aoff ^ 16));                    \
            u32 h0 = __builtin_amdgcn_perm(xa.y, xa.x, PSEL);                \
            u32 h1 = __builtin_amdgcn_perm(xa.w, xa.z, PSEL);                \
            u32 h2 = __builtin_amdgcn_perm(xv.y, xv.x, PSEL);                \
            u32 h3 = __builtin_amdgcn_perm(xv.w, xv.z, PSEL);                \
            float d0 = u2f(xa.x) - u2f(xa.x & 0xFFFF0000u);                  \
            float d1 = u2f(xa.y) - u2f(xa.y & 0xFFFF0000u);                  \
            float d2 = u2f(xa.z) - u2f(xa.z & 0xFFFF0000u);                  \
            float d3 = u2f(xa.w) - u2f(xa.w & 0xFFFF0000u);                  \
            float d4 = u2f(xv.x) - u2f(xv.x & 0xFFFF0000u);                  \
            float d5 = u2f(xv.y) - u2f(xv.y & 0xFFFF0000u);                  \
            float d6 = u2f(xv.z) - u2f(xv.z & 0xFFFF0000u);                  \
            float d7 = u2f(xv.w) - u2f(xv.w & 0xFFFF0000u);                  \
            u32 g0 = __builtin_amdgcn_perm(f2u(d1), f2u(d0), PSEL);          \
            u32 g1 = __builtin_amdgcn_perm(f2u(d3), f2u(d2), PSEL);          \
            u32 g2 = __builtin_amdgcn_perm(f2u(d5), f2u(d4), PSEL);          \
            u32 g3 = __builtin_amdgcn_perm(f2u(d7), f2u(d6), PSEL);          \
            bf16x8 ahi = __builtin_bit_cast(bf16x8, (u32x4){h0, h1, h2, h3});\
            bf16x8 alo = __builtin_bit_cast(bf16x8, (u32x4){g0, g1, g2, g3});\
            _Pragma("unroll")                                                \
            for (int n = 0; n < 8; ++n) {                                    \
                bf16x8 bh = __builtin_bit_cast(bf16x8, wregH[n * 2 + ks]);   \
                bf16x8 bl = __builtin_bit_cast(bf16x8, wregL[n * 2 + ks]);   \
                zacc[n] = mfma16(ahi, bh, zacc[n]);                          \
                zacc[n] = mfma16(ahi, bl, zacc[n]);                          \
                zacc[n] = mfma16(alo, bh, zacc[n]);                          \
            }                                                                \
        }                                                                    \
        f32x4* zo = (f32x4*)zbufC + ((mm) & 1) * 512 + lr * 128 + lc;        \
        _Pragma("unroll")                                                    \
        for (int n = 0; n < 8; ++n) zo[n * 16] = zacc[n];                    \
    }

#define STEP_BODY(Z0, Z1)                                                    \
    {                                                                        \
        shC[kl] = h;                                                         \
        float4 hq[8];                                                        \
        _Pragma("unroll")                                                    \
        for (int q = 0; q < 8; ++q) hq[q] = shq[q];                          \
        f32x2 a0 = {(Z0), 0.0f}, b0 = {0.0f, 0.0f};                          \
        f32x2 a1v = {(Z1), 0.0f}, b1 = {0.0f, 0.0f};                         \
        _Pragma("unroll")                                                    \
        for (int q = 0; q < 8; ++q) {                                        \
            f32x2 hlo = {hq[q].x, hq[q].y};                                  \
            f32x2 hhi = {hq[q].z, hq[q].w};                                  \
            a0  = __builtin_elementwise_fma(hlo, wh0p[2 * q],     a0);       \
            b0  = __builtin_elementwise_fma(hhi, wh0p[2 * q + 1], b0);       \
            a1v = __builtin_elementwise_fma(hlo, wh1p[2 * q],     a1v);      \
            b1  = __builtin_elementwise_fma(hhi, wh1p[2 * q + 1], b1);       \
        }                                                                    \
        f32x2 s0p = a0 + b0;                                                 \
        f32x2 s1p = a1v + b1;                                                \
        float A0 = s0p[0] + s0p[1];                                          \
        float A1 = s1p[0] + s1p[1];                                          \
        float act0 = sigmoid_f(A0);                                          \
        float u1 = fast_rcp(1.0f + fast_exp2(A1 * s1));                      \
        float act1 = fmaf(u1, m1, a1);                                       \
        float gi = act0, gf = act0;                                          \
        asm("v_permlane32_swap_b32 %0, %1" : "+v"(gi), "+v"(gf));            \
        float gg = act1, go = act1;                                          \
        asm("v_permlane32_swap_b32 %0, %1" : "+v"(gg), "+v"(go));            \
        c = fmaf(gf, c, gi * gg);                                            \
        float uc = fast_rcp(1.0f + fast_exp2(c * -2.88539008177792681472f)); \
        float tc2 = fmaf(uc, 2.0f, -1.0f);                                   \
        h = go * tc2;                                                        \
    }

    // ---- prologue: producers fill zbuf[ci][0] ----
    if (role == 1) {
        GLOAD(0)
        GLOAD(1)
        asm volatile("s_waitcnt vmcnt(4)" ::: "memory");   // X_0 landed
        ZPREP(0)
    }
    __syncthreads();

    for (int m = 0; m < NCH; ++m) {
        if (role == 1) {
            if (m + 1 < NCH) {
                if (m + 2 < NCH) {
                    GLOAD(m + 2)
                    asm volatile("s_waitcnt vmcnt(4)" ::: "memory");
                } else {
                    asm volatile("s_waitcnt vmcnt(0)" ::: "memory");
                }
                ZPREP(m + 1)
            }
        } else if (role == 0) {
            const float4* zb = (const float4*)zbufC + (m & 1) * 512;
            float4 z0q[4], z1q[4];
#pragma unroll
            for (int u4 = 0; u4 < 4; ++u4) {
                z0q[u4] = zb[u4 * 128 + l];
                z1q[u4] = zb[u4 * 128 + 64 + l];
            }
#pragma unroll
            for (int u4 = 0; u4 < 4; ++u4) {
                STEP_BODY(z0q[u4].x, z1q[u4].x)
                STEP_BODY(z0q[u4].y, z1q[u4].y)
                STEP_BODY(z0q[u4].z, z1q[u4].z)
                STEP_BODY(z0q[u4].w, z1q[u4].w)
            }
        }
        // idle waves (role 2,3) just match barriers
        __syncthreads();
    }

#undef STEP_BODY
#undef ZPREP
#undef GLOAD

    // ---- head: out = elu(h_T) @ Wd + bd (consumer waves only) ----
    if (role == 0) {
        float e = (h > 0.0f) ? h : (fast_exp2(h * L2E) - 1.0f);
#pragma unroll
        for (int q = 0; q < FUT; ++q) {
            float v = lowHalf ? e * Wd[kl * FUT + q] : 0.0f;
#pragma unroll
            for (int off = 1; off < 64; off <<= 1)
                v += __shfl_xor(v, off);
            if (l == 0) out[b * FUT + q] = v + bd[q];
        }
    }
}

// ---------------------------------------------------------------------------
extern "C" void kernel_launch(void* const* d_in, const int* in_sizes, int n_in,
                              void* d_out, int out_size, void* d_ws, size_t ws_size,
                              hipStream_t stream)
{
    const float* X    = (const float*)d_in[0];
    const float* Wx   = (const float*)d_in[1];
    const float* Wh   = (const float*)d_in[2];
    const float* bias = (const float*)d_in[3];
    const float* Wd   = (const float*)d_in[4];
    const float* bd   = (const float*)d_in[5];
    float* out = (float*)d_out;

    lstm_fused<<<dim3(BSZ / 2), dim3(512), 0, stream>>>(X, Wx, bias, Wh, Wd, bd, out);
}

// Round 14
// 349.654 us; speedup vs baseline: 1.6460x; 1.6460x over previous
//
#include <hip/hip_runtime.h>

#define FOUR_H 128
#define FUT 6
#define BSZ 256
#define TT 2048
#define FF 64
#define CH 16
#define NCH (TT / CH)              // 128 chunks of 16 timesteps

typedef float f32x2 __attribute__((ext_vector_type(2)));
typedef float f32x4 __attribute__((ext_vector_type(4)));
typedef unsigned int u32;
typedef u32 u32x4 __attribute__((ext_vector_type(4)));
typedef short bf16x8 __attribute__((ext_vector_type(8)));

__device__ __forceinline__ float fast_rcp(float x)  { return __builtin_amdgcn_rcpf(x); }
__device__ __forceinline__ float fast_exp2(float x) { return __builtin_amdgcn_exp2f(x); }
__device__ __forceinline__ float sigmoid_f(float x) {
    float t = fast_exp2(x * -1.44269504088896340736f);
    return fast_rcp(1.0f + t);
}
__device__ __forceinline__ u32 f2u(float x) { return __builtin_bit_cast(u32, x); }
__device__ __forceinline__ float u2f(u32 x) { return __builtin_bit_cast(float, x); }

__device__ __forceinline__ void gload_lds16(const void* g, void* l) {
    __builtin_amdgcn_global_load_lds(
        (const __attribute__((address_space(1))) void*)g,
        (__attribute__((address_space(3))) void*)l, 16, 0, 0);
}

__device__ __forceinline__ f32x4 mfma16(bf16x8 a, bf16x8 b, f32x4 c) {
    return __builtin_amdgcn_mfma_f32_16x16x32_bf16(a, b, c, 0, 0, 0);
}

// ===========================================================================
// 256 blocks x 2 waves. Block b owns batch b.
//   wave 0 (SIMD i): the serial LSTM scan — proven step body, NOTHING else.
//   wave 1 (SIMD j != i): X prefetch (global_load_lds, 2-deep) + split-bf16
//     MFMA x-projection into double-buffered zbuf. One __syncthreads per
//     16-step chunk hands zbuf halves over; wave 1 is ~9x faster per chunk
//     so it parks at the barrier.
// ===========================================================================
__global__ __launch_bounds__(128) void lstm_fused(
    const float* __restrict__ X, const float* __restrict__ Wx,
    const float* __restrict__ bias, const float* __restrict__ Wh,
    const float* __restrict__ Wd, const float* __restrict__ bd,
    float* __restrict__ out)
{
    __shared__ float xstage[2 * CH * FF];     // 8 KB  X double buffer (wave 1)
    __shared__ float zbuf[2 * CH * FOUR_H];   // 16 KB Z double buffer (1 -> 0)
    __shared__ u32x4 wfrag[8 * 2 * 2 * 64];   // 32 KB Wx bf16 hi/lo frags (wave 1)
    __shared__ float sh[32];                  // h broadcast slab (wave 0)

    int wv = threadIdx.x >> 6;
    int b  = blockIdx.x;
    int l  = threadIdx.x & 63;
    int kl = l & 31;
    int lr = l >> 4;       // lane k-group 0..3
    int lc = l & 15;       // lane row/col within tile
    bool lowHalf = (l < 32);

    const u32 PSEL = 0x07060302u;   // perm: {b0.hi16, b1.hi16} -> one u32
    const char* Xb = (const char*)(X + (size_t)b * TT * FF);

    // ---------------- wave-0 state (consumer) ----------------
    f32x2 wh0p[16], wh1p[16];
    float c = 0.0f, h = 0.0f;
    const float4* shq = (const float4*)sh;
    const float L2E = 1.44269504088896340736f;
    float s1 = lowHalf ? (-2.0f * L2E) : (-L2E);
    float m1 = lowHalf ? 2.0f : 1.0f;
    float a1 = lowHalf ? -1.0f : 0.0f;

    // ---------------- wave-1 state (producer) ----------------
    float bj[8];
    int soff[4];

    if (wv == 0) {
#pragma unroll
        for (int m = 0; m < 16; ++m) {
            wh0p[m][0] = Wh[(2 * m) * FOUR_H + l];
            wh0p[m][1] = Wh[(2 * m + 1) * FOUR_H + l];
            wh1p[m][0] = Wh[(2 * m) * FOUR_H + 64 + l];
            wh1p[m][1] = Wh[(2 * m + 1) * FOUR_H + 64 + l];
        }
    } else {
#pragma unroll
        for (int n = 0; n < 8; ++n) bj[n] = bias[n * 16 + lc];
        // XOR-preswizzled gload source offsets (4KB chunk, 16B units):
        // LDS slot (t, q') holds global chunk q = q' ^ t
#pragma unroll
        for (int i = 0; i < 4; ++i) {
            int t = i * 4 + lr;
            soff[i] = t * 256 + ((lc ^ t) << 4);
        }
        // one-time: split Wx into bf16 hi/lo B-fragments in LDS.
        // B-frag tile n, kstep ks: lane l holds B[k][j], j=n*16+lc,
        // k = ks*32 + lr*8 + e, packed 2 bf16/u32 (even elem low).
#pragma unroll 2
        for (int n = 0; n < 8; ++n)
            for (int ks = 0; ks < 2; ++ks) {
                u32 hi[4], lo[4];
#pragma unroll
                for (int e = 0; e < 4; ++e) {
                    int k0 = ks * 32 + lr * 8 + 2 * e;
                    float w0 = Wx[k0 * FOUR_H + n * 16 + lc];
                    float w1 = Wx[(k0 + 1) * FOUR_H + n * 16 + lc];
                    u32 x0 = f2u(w0), x1 = f2u(w1);
                    hi[e] = __builtin_amdgcn_perm(x1, x0, PSEL);
                    float l0 = w0 - u2f(x0 & 0xFFFF0000u);
                    float l1 = w1 - u2f(x1 & 0xFFFF0000u);
                    lo[e] = __builtin_amdgcn_perm(f2u(l1), f2u(l0), PSEL);
                }
                wfrag[((n * 2 + ks) * 2 + 0) * 64 + l] = (u32x4){hi[0], hi[1], hi[2], hi[3]};
                wfrag[((n * 2 + ks) * 2 + 1) * 64 + l] = (u32x4){lo[0], lo[1], lo[2], lo[3]};
            }
    }

#define GLOAD(mm)                                                            \
    {                                                                        \
        const char* src = Xb + (size_t)(mm) * 4096;                          \
        char* dst = (char*)xstage + ((mm) & 1) * 4096;                       \
        _Pragma("unroll")                                                    \
        for (int i = 0; i < 4; ++i)                                          \
            gload_lds16(src + soff[i], dst + i * 1024);                      \
    }

    // Z for chunk mm: A-frag row=lc, k = ks*32+lr*8+e (swizzled read);
    // 3 MFMAs per (n,ks): hi*hi + hi*lo + lo*hi. D row=(lr*4+r), col=lc.
#define ZPREP(mm)                                                            \
    {                                                                        \
        f32x4 zacc[8];                                                       \
        _Pragma("unroll")                                                    \
        for (int n = 0; n < 8; ++n)                                          \
            zacc[n] = (f32x4){bj[n], bj[n], bj[n], bj[n]};                   \
        const char* xs = (const char*)xstage + ((mm) & 1) * 4096;            \
        _Pragma("unroll")                                                    \
        for (int ks = 0; ks < 2; ++ks) {                                     \
            int q0 = ks * 8 + lr * 2;                                        \
            int aoff = lc * 256 + ((q0 ^ lc) << 4);                          \
            u32x4 xa = *(const u32x4*)(xs + aoff);                           \
            u32x4 xv = *(const u32x4*)(xs + (aoff ^ 16));                    \
            u32 h0 = __builtin_amdgcn_perm(xa.y, xa.x, PSEL);                \
            u32 h1 = __builtin_amdgcn_perm(xa.w, xa.z, PSEL);                \
            u32 h2 = __builtin_amdgcn_perm(xv.y, xv.x, PSEL);                \
            u32 h3 = __builtin_amdgcn_perm(xv.w, xv.z, PSEL);                \
            float d0 = u2f(xa.x) - u2f(xa.x & 0xFFFF0000u);                  \
            float d1 = u2f(xa.y) - u2f(xa.y & 0xFFFF0000u);                  \
            float d2 = u2f(xa.z) - u2f(xa.z & 0xFFFF0000u);                  \
            float d3 = u2f(xa.w) - u2f(xa.w & 0xFFFF0000u);                  \
            float d4 = u2f(xv.x) - u2f(xv.x & 0xFFFF0000u);                  \
            float d5 = u2f(xv.y) - u2f(xv.y & 0xFFFF0000u);                  \
            float d6 = u2f(xv.z) - u2f(xv.z & 0xFFFF0000u);                  \
            float d7 = u2f(xv.w) - u2f(xv.w & 0xFFFF0000u);                  \
            u32 g0 = __builtin_amdgcn_perm(f2u(d1), f2u(d0), PSEL);          \
            u32 g1 = __builtin_amdgcn_perm(f2u(d3), f2u(d2), PSEL);          \
            u32 g2 = __builtin_amdgcn_perm(f2u(d5), f2u(d4), PSEL);          \
            u32 g3 = __builtin_amdgcn_perm(f2u(d7), f2u(d6), PSEL);          \
            bf16x8 ahi = __builtin_bit_cast(bf16x8, (u32x4){h0, h1, h2, h3});\
            bf16x8 alo = __builtin_bit_cast(bf16x8, (u32x4){g0, g1, g2, g3});\
            _Pragma("unroll")                                                \
            for (int n = 0; n < 8; ++n) {                                    \
                bf16x8 bh = __builtin_bit_cast(bf16x8,                       \
                    wfrag[((n * 2 + ks) * 2 + 0) * 64 + l]);                 \
                bf16x8 bl = __builtin_bit_cast(bf16x8,                       \
                    wfrag[((n * 2 + ks) * 2 + 1) * 64 + l]);                 \
                zacc[n] = mfma16(ahi, bh, zacc[n]);                          \
                zacc[n] = mfma16(ahi, bl, zacc[n]);                          \
                zacc[n] = mfma16(alo, bh, zacc[n]);                          \
            }                                                                \
        }                                                                    \
        f32x4* zo = (f32x4*)zbuf + ((mm) & 1) * 512 + lr * 128 + lc;         \
        _Pragma("unroll")                                                    \
        for (int n = 0; n < 8; ++n) zo[n * 16] = zacc[n];                    \
    }

#define STEP_BODY(Z0, Z1)                                                    \
    {                                                                        \
        sh[kl] = h;                                                          \
        float4 hq[8];                                                        \
        _Pragma("unroll")                                                    \
        for (int q = 0; q < 8; ++q) hq[q] = shq[q];                          \
        f32x2 a0 = {(Z0), 0.0f}, b0 = {0.0f, 0.0f};                          \
        f32x2 a1v = {(Z1), 0.0f}, b1 = {0.0f, 0.0f};                         \
        _Pragma("unroll")                                                    \
        for (int q = 0; q < 8; ++q) {                                        \
            f32x2 hlo = {hq[q].x, hq[q].y};                                  \
            f32x2 hhi = {hq[q].z, hq[q].w};                                  \
            a0  = __builtin_elementwise_fma(hlo, wh0p[2 * q],     a0);       \
            b0  = __builtin_elementwise_fma(hhi, wh0p[2 * q + 1], b0);       \
            a1v = __builtin_elementwise_fma(hlo, wh1p[2 * q],     a1v);      \
            b1  = __builtin_elementwise_fma(hhi, wh1p[2 * q + 1], b1);       \
        }                                                                    \
        f32x2 s0p = a0 + b0;                                                 \
        f32x2 s1p = a1v + b1;                                                \
        float A0 = s0p[0] + s0p[1];                                          \
        float A1 = s1p[0] + s1p[1];                                          \
        float act0 = sigmoid_f(A0);                                          \
        float u1 = fast_rcp(1.0f + fast_exp2(A1 * s1));                      \
        float act1 = fmaf(u1, m1, a1);                                       \
        float gi = act0, gf = act0;                                          \
        asm("v_permlane32_swap_b32 %0, %1" : "+v"(gi), "+v"(gf));            \
        float gg = act1, go = act1;                                          \
        asm("v_permlane32_swap_b32 %0, %1" : "+v"(gg), "+v"(go));            \
        c = fmaf(gf, c, gi * gg);                                            \
        float uc = fast_rcp(1.0f + fast_exp2(c * -2.88539008177792681472f)); \
        float tc2 = fmaf(uc, 2.0f, -1.0f);                                   \
        h = go * tc2;                                                        \
    }

    // ---- prologue: wave 1 fills zbuf[0] ----
    if (wv == 1) {
        GLOAD(0)
        GLOAD(1)
        asm volatile("s_waitcnt vmcnt(4)" ::: "memory");   // X_0 landed
        ZPREP(0)
    }
    __syncthreads();

    for (int m = 0; m < NCH; ++m) {
        if (wv == 1) {
            // produce chunk m+1 into zbuf[(m+1)&1] while wave 0 eats zbuf[m&1]
            if (m + 1 < NCH) {
                if (m + 2 < NCH) {
                    GLOAD(m + 2)
                    asm volatile("s_waitcnt vmcnt(4)" ::: "memory");  // X_{m+1} landed
                } else {
                    asm volatile("s_waitcnt vmcnt(0)" ::: "memory");
                }
                ZPREP(m + 1)
            }
        } else {
            const float4* zb = (const float4*)zbuf + (m & 1) * 512;
            float4 z0q[4], z1q[4];
#pragma unroll
            for (int u4 = 0; u4 < 4; ++u4) {
                z0q[u4] = zb[u4 * 128 + l];
                z1q[u4] = zb[u4 * 128 + 64 + l];
            }
#pragma unroll
            for (int u4 = 0; u4 < 4; ++u4) {
                STEP_BODY(z0q[u4].x, z1q[u4].x)
                STEP_BODY(z0q[u4].y, z1q[u4].y)
                STEP_BODY(z0q[u4].z, z1q[u4].z)
                STEP_BODY(z0q[u4].w, z1q[u4].w)
            }
        }
        __syncthreads();
    }

#undef STEP_BODY
#undef ZPREP
#undef GLOAD

    // ---- head: out = elu(h_T) @ Wd + bd (wave 0 only) ----
    if (wv == 0) {
        float e = (h > 0.0f) ? h : (fast_exp2(h * L2E) - 1.0f);
#pragma unroll
        for (int q = 0; q < FUT; ++q) {
            float v = lowHalf ? e * Wd[kl * FUT + q] : 0.0f;
#pragma unroll
            for (int off = 1; off < 64; off <<= 1)
                v += __shfl_xor(v, off);
            if (l == 0) out[b * FUT + q] = v + bd[q];
        }
    }
}

// ---------------------------------------------------------------------------
extern "C" void kernel_launch(void* const* d_in, const int* in_sizes, int n_in,
                              void* d_out, int out_size, void* d_ws, size_t ws_size,
                              hipStream_t stream)
{
    const float* X    = (const float*)d_in[0];
    const float* Wx   = (const float*)d_in[1];
    const float* Wh   = (const float*)d_in[2];
    const float* bias = (const float*)d_in[3];
    const float* Wd   = (const float*)d_in[4];
    const float* bd   = (const float*)d_in[5];
    float* out = (float*)d_out;

    lstm_fused<<<dim3(BSZ), dim3(128), 0, stream>>>(X, Wx, bias, Wh, Wd, bd, out);
}